// Round 9
// baseline (179.403 us; speedup 1.0000x reference)
//
#include <hip/hip_runtime.h>
#include <math.h>

// ---------------------------------------------------------------------------
// Threefry-2x32 (JAX), 20 rounds. Exact integer arithmetic.
// ---------------------------------------------------------------------------
#define TFROT(v, r) __builtin_amdgcn_alignbit((v), (v), 32 - (r))

__device__ __forceinline__ void tf_block(unsigned k0, unsigned k1,
                                         unsigned x0, unsigned x1,
                                         unsigned &o0, unsigned &o1) {
  unsigned ks2 = k0 ^ k1 ^ 0x1BD11BDAu;
  x0 += k0; x1 += k1;
  x0 += x1; x1 = TFROT(x1, 13); x1 ^= x0;
  x0 += x1; x1 = TFROT(x1, 15); x1 ^= x0;
  x0 += x1; x1 = TFROT(x1, 26); x1 ^= x0;
  x0 += x1; x1 = TFROT(x1,  6); x1 ^= x0;
  x0 += k1; x1 += ks2 + 1u;
  x0 += x1; x1 = TFROT(x1, 17); x1 ^= x0;
  x0 += x1; x1 = TFROT(x1, 29); x1 ^= x0;
  x0 += x1; x1 = TFROT(x1, 16); x1 ^= x0;
  x0 += x1; x1 = TFROT(x1, 24); x1 ^= x0;
  x0 += ks2; x1 += k0 + 2u;
  x0 += x1; x1 = TFROT(x1, 13); x1 ^= x0;
  x0 += x1; x1 = TFROT(x1, 15); x1 ^= x0;
  x0 += x1; x1 = TFROT(x1, 26); x1 ^= x0;
  x0 += x1; x1 = TFROT(x1,  6); x1 ^= x0;
  x0 += k0; x1 += k1 + 3u;
  x0 += x1; x1 = TFROT(x1, 17); x1 ^= x0;
  x0 += x1; x1 = TFROT(x1, 29); x1 ^= x0;
  x0 += x1; x1 = TFROT(x1, 16); x1 ^= x0;
  x0 += x1; x1 = TFROT(x1, 24); x1 ^= x0;
  x0 += k1; x1 += ks2 + 4u;
  x0 += x1; x1 = TFROT(x1, 13); x1 ^= x0;
  x0 += x1; x1 = TFROT(x1, 15); x1 ^= x0;
  x0 += x1; x1 = TFROT(x1, 26); x1 ^= x0;
  x0 += x1; x1 = TFROT(x1,  6); x1 ^= x0;
  x0 += ks2; x1 += k0 + 5u;
  o0 = x0; o1 = x1;
}

// partitionable random_bits(32) word for flat index i: out0 ^ out1
__device__ __forceinline__ unsigned tf_bits32(unsigned k0, unsigned k1, unsigned i) {
  unsigned o0, o1;
  tf_block(k0, k1, 0u, i, o0, o1);
  return o0 ^ o1;
}

// ---------------------------------------------------------------------------
// XLA:CPU f32 exp (GenerateVF32Exp — Cephes sequential Horner, UNFUSED).
// ---------------------------------------------------------------------------
__device__ __forceinline__ float xla_exp_f32(float x) {
#pragma clang fp contract(off)
  const float kHi = 88.3762626647950f;
  const float kLo = -88.3762626647949f;
  const float kLog2e = 1.44269504088896341f;
  const float kC1 = 0.693359375f;
  const float kC2 = -2.12194440e-4f;
  const float p0 = 1.9875691500e-4f, p1 = 1.3981999507e-3f,
              p2 = 8.3334519073e-3f, p3 = 4.1665795894e-2f,
              p4 = 1.6666665459e-1f, p5 = 5.0000001201e-1f;
  float xc = fminf(fmaxf(x, kLo), kHi);
  float t = xc * kLog2e;
  t = t + 0.5f;
  float fx = floorf(t);
  float tmp = kC1 * fx;
  float z = kC2 * fx;
  float xr = xc - tmp;
  xr = xr - z;
  z = xr * xr;
  float y = p0 * xr;  y = y + p1;
  y = y * xr;  y = y + p2;
  y = y * xr;  y = y + p3;
  y = y * xr;  y = y + p4;
  y = y * xr;  y = y + p5;
  y = y * z;   y = y + xr;
  y = 1.0f + y;
  int emm0 = (int)fx;
  emm0 = (emm0 + 0x7f) << 23;
  float two_n = __int_as_float(emm0);
  float res = y * two_n;
  return fmaxf(res, x);   // max with ORIGINAL input (XLA)
}

// ---------------------------------------------------------------------------
// XLA:CPU f32 log (GenerateVF32Log — Eigen 3.3 AVX plog port, UNFUSED).
// ---------------------------------------------------------------------------
__device__ __forceinline__ float xla_log_f32(float x) {
#pragma clang fp contract(off)
  const float kSqrtHf = 0.707106781186547524f;
  const float p0 = 7.0376836292e-2f,  p1 = -1.1514610310e-1f,
              p2 = 1.1676998740e-1f,  p3 = -1.2420140846e-1f,
              p4 = 1.4249322787e-1f,  p5 = -1.6668057665e-1f,
              p6 = 2.0000714765e-1f,  p7 = -2.4999993993e-1f,
              p8 = 3.3333331174e-1f;
  const float q1 = -2.12194440e-4f, q2 = 0.693359375f;
  float t0 = fmaxf(x, __uint_as_float(0x00800000u));  // min normal pos
  unsigned ib = __float_as_uint(t0);
  int ei = (int)(ib >> 23) - 0x7f;
  float e = (float)ei;
  e = e + 1.0f;
  t0 = __uint_as_float((ib & 0x807fffffu) | 0x3f000000u);  // mantissa [0.5,1)
  bool m = (t0 < kSqrtHf);
  float tmp1 = m ? t0 : 0.0f;
  t0 = t0 - 1.0f;
  e = e - (m ? 1.0f : 0.0f);
  t0 = t0 + tmp1;
  float x2 = t0 * t0;
  float x3 = x2 * t0;
  float y, y1, y2;
  y  = p0 * t0;  y  = y  + p1;
  y1 = p3 * t0;  y1 = y1 + p4;
  y2 = p6 * t0;  y2 = y2 + p7;
  y  = y  * t0;  y  = y  + p2;
  y1 = y1 * t0;  y1 = y1 + p5;
  y2 = y2 * t0;  y2 = y2 + p8;
  y  = y * x3;   y  = y + y1;
  y  = y * x3;   y  = y + y2;
  y  = y * x3;
  y1 = e * q1;
  float tmp2 = x2 * 0.5f;
  y = y + y1;
  t0 = t0 - tmp2;
  y2 = e * q2;
  t0 = t0 + y;
  t0 = t0 + y2;
  return t0;
}

// uniform [0,1) from 32 random bits, exactly as jax._src.random._uniform
__device__ __forceinline__ float bits_to_f01(unsigned b) {
#pragma clang fp contract(off)
  return __uint_as_float((b >> 9) | 0x3f800000u) - 1.0f;
}

// f32 Giles erfinv — continuous path only (abs slack ~0.1; err ~1e-6)
__device__ __forceinline__ float erfinv_f(float x) {
  float t = fmaf(-x, x, 1.0f);
  float w = -__logf(t);
  float p;
  if (w < 5.0f) {
    float v = w - 2.5f;
    p = 2.81022636e-08f;
    p = fmaf(p, v, 3.43273939e-07f);
    p = fmaf(p, v, -3.5233877e-06f);
    p = fmaf(p, v, -4.39150654e-06f);
    p = fmaf(p, v, 0.00021858087f);
    p = fmaf(p, v, -0.00125372503f);
    p = fmaf(p, v, -0.00417768164f);
    p = fmaf(p, v, 0.246640727f);
    p = fmaf(p, v, 1.50140941f);
  } else {
    float v = __fsqrt_rn(w) - 3.0f;
    p = -0.000200214257f;
    p = fmaf(p, v, 0.000100950558f);
    p = fmaf(p, v, 0.00134934322f);
    p = fmaf(p, v, -0.00367342844f);
    p = fmaf(p, v, 0.00573950773f);
    p = fmaf(p, v, -0.0076224613f);
    p = fmaf(p, v, 0.00943887047f);
    p = fmaf(p, v, 1.00167406f);
    p = fmaf(p, v, 2.83297682f);
  }
  return p * x;
}

struct Params {
  double mu[6];     // mus (3,2) row-major
  double Rs[3];
  float logits[5];  // log(wf) — exact slow-path scores
  float invw[5];    // 1/wf — fast exponential-race coefficients
  unsigned keys[8]; // kcat, kth, kr, keps (2 words each)
};

// ---------------------------------------------------------------------------
// Kernel 1: single-block prep, UNCHANGED bitwise math from passing rounds.
// ---------------------------------------------------------------------------
__global__ void prep_kernel(const float* __restrict__ c, const float* __restrict__ h,
                            const float* __restrict__ W1, const float* __restrict__ b1,
                            const float* __restrict__ W2, const float* __restrict__ b2,
                            const float* __restrict__ W3, const float* __restrict__ b3,
                            const float* __restrict__ Wmu, const float* __restrict__ bmu,
                            const float* __restrict__ WR, const float* __restrict__ bR,
                            Params* __restrict__ P) {
#pragma clang fp contract(off)
  __shared__ float xs[192], z1[128], z2[128], z3[5];
  int t = threadIdx.x;
  if (t < 64) xs[t] = c[t];
  else if (t < 192) xs[t] = h[t - 64];
  __syncthreads();
  if (t < 128) {
    float acc = 0.0f;
    for (int k = 0; k < 192; ++k) { float pr = xs[k] * W1[k * 128 + t]; acc = acc + pr; }
    acc = acc + b1[t];
    float ex = xla_exp_f32(-acc);
    float den = 1.0f + ex;
    float sg = 1.0f / den;
    z1[t] = acc * sg;
  }
  __syncthreads();
  if (t < 128) {
    float acc = 0.0f;
    for (int k = 0; k < 128; ++k) { float pr = z1[k] * W2[k * 128 + t]; acc = acc + pr; }
    acc = acc + b2[t];
    float ex = xla_exp_f32(-acc);
    float den = 1.0f + ex;
    float sg = 1.0f / den;
    z2[t] = acc * sg;
  }
  __syncthreads();
  if (t < 5) {
    float acc = 0.0f;
    for (int k = 0; k < 128; ++k) { float pr = z2[k] * W3[k * 5 + t]; acc = acc + pr; }
    z3[t] = acc + b3[t];
  }
  if (t < 6) {
    double acc = 0.0;
    for (int k = 0; k < 192; ++k) acc += (double)xs[k] * (double)Wmu[k * 6 + t];
    P->mu[t] = acc + (double)bmu[t];
  }
  if (t < 3) {
    double acc = 0.0;
    for (int k = 0; k < 192; ++k) acc += (double)xs[k] * (double)WR[k * 3 + t];
    P->Rs[t] = acc + (double)bR[t];
  }
  __syncthreads();
  if (t == 0) {
    float mx = z3[0];
    for (int j = 1; j < 5; ++j) mx = fmaxf(mx, z3[j]);
    float ev[5];
    float ssum = 0.0f;
    for (int j = 0; j < 5; ++j) {
      float d = z3[j] - mx;
      ev[j] = xla_exp_f32(d);
      ssum = ssum + ev[j];
    }
    float w[5];
    for (int j = 0; j < 5; ++j) w[j] = ev[j] / ssum;
    float wbg = fminf(w[4], 0.15f);
    float rsum = 0.0f;
    for (int j = 0; j < 4; ++j) rsum = rsum + w[j];
    float rs = fmaxf(rsum, 1e-8f);
    float om = 1.0f - wbg;
    float wf[5];
    for (int j = 0; j < 4; ++j) {
      float a = w[j] * om;
      float bq = a / rs;
      wf[j] = bq + 1e-8f;
    }
    wf[4] = wbg + 1e-8f;
    for (int j = 0; j < 5; ++j) {
      P->logits[j] = xla_log_f32(wf[j]);
      P->invw[j] = 1.0f / wf[j];
    }
    unsigned a0, a1;
    tf_block(0u, 42u, 0u, 0u, a0, a1); P->keys[0] = a0; P->keys[1] = a1;  // k_cat
    tf_block(0u, 42u, 0u, 1u, a0, a1); P->keys[2] = a0; P->keys[3] = a1;  // k_th
    tf_block(0u, 42u, 0u, 2u, a0, a1); P->keys[4] = a0; P->keys[5] = a1;  // k_r
    tf_block(0u, 42u, 0u, 3u, a0, a1); P->keys[6] = a0; P->keys[7] = a1;  // k_eps
  }
}

// ---------------------------------------------------------------------------
// One sample: exponential-race categorical (guarded exact recompute) +
// branch-free ring/eps tail. Arithmetic byte-identical to the passing R8,
// except the guard's relative margin tightened 1e-3 -> 1e-4 (still ~100x
// the fast-vs-exact perturbation bound; only changes WHICH lanes take the
// exact path, never the chosen index).
// ---------------------------------------------------------------------------
__device__ __forceinline__ void do_sample(unsigned sU,
                                          const float* lg, const float* cw,
                                          const float* muf, const float* Rsf,
                                          const unsigned* ky,
                                          float& ox, float& oy, int& biOut) {
#pragma clang fp contract(off)
  const float TINYF = __uint_as_float(0x00800000u);   // f32 tiny (min normal)
  const float LOF   = __uint_as_float(0xBF7FFFFFu);   // nextafter(-1,0)
  const float SQRT2F = 1.4142135623730951f;

  unsigned base = 5u * sU;
  unsigned bb[5];
  int bi = 0;
  float m1 = __builtin_inff();
  float m2 = __builtin_inff();
#pragma unroll
  for (int j = 0; j < 5; ++j) {
    unsigned b = tf_bits32(ky[0], ky[1], base + (unsigned)j);
    bb[j] = b;
    float u0 = bits_to_f01(b);
    float e2 = -__log2f(u0);           // +inf when u0 == 0 (never argmin)
    float m = e2 * cw[j];
    bool lt = m < m1;
    float old1 = m1;
    m1 = lt ? m : m1;
    m2 = lt ? old1 : fminf(m2, m);
    bi = lt ? j : bi;
  }
  // guard: relative margin, tiny-m floor (hw-log error regime), inf runner-up
  bool slow = (m2 - m1 < 1e-4f * m2) || (m1 < 1e-4f) || (m2 > 1e37f);
  if (slow) {
    // exact recompute: bitwise-XLA chain, first-max-wins
    int best = 0;
    float bestv = -__builtin_inff();
#pragma unroll
    for (int j = 0; j < 5; ++j) {
      float u0 = bits_to_f01(bb[j]);
      float u = u0 + TINYF;
      u = fmaxf(TINYF, u);
      float l1 = xla_log_f32(u);
      float nl1 = -l1;
      float l2 = xla_log_f32(nl1);
      float g = -l2;
      float sc = g + lg[j];
      if (sc > bestv) { bestv = sc; best = j; }
    }
    bi = best;
  }

  // branch-free tail: 2 shared threefry blocks, both results, select
  bool ring = bi < 3;
  unsigned cA = ring ? sU : 2u * sU;
  unsigned cB = ring ? sU : 2u * sU + 1u;
  unsigned kA0 = ring ? ky[2] : ky[6];
  unsigned kA1 = ring ? ky[3] : ky[7];
  unsigned kB0 = ring ? ky[4] : ky[6];
  unsigned kB1 = ring ? ky[5] : ky[7];
  unsigned bA = tf_bits32(kA0, kA1, cA);
  unsigned bB = tf_bits32(kB0, kB1, cB);

  float a01 = bits_to_f01(bA);         // ring: theta in revolutions; eps: uA
  float b01 = bits_to_f01(bB);
  float uB = fmaxf(LOF, fmaf(b01, 2.0f, LOF));
  float nB = SQRT2F * erfinv_f(uB);    // ring: r-noise; eps: y-normal

  // ring result (hw sin/cos take revolutions: sin(2*pi*a01))
  float Rb  = (bi == 0) ? Rsf[0] : ((bi == 1) ? Rsf[1] : Rsf[2]);
  float mxr = (bi == 0) ? muf[0] : ((bi == 1) ? muf[2] : muf[4]);
  float myr = (bi == 0) ? muf[1] : ((bi == 1) ? muf[3] : muf[5]);
  float r = fmaf(0.02f, nB, Rb);
  float rx = fmaf(r, __builtin_amdgcn_cosf(a01), mxr);
  float ry = fmaf(r, __builtin_amdgcn_sinf(a01), myr);

  // eps result
  float uA = fmaxf(LOF, fmaf(a01, 2.0f, LOF));
  float nA = SQRT2F * erfinv_f(uA);
  float sg = (bi == 3) ? 0.01f : 0.94f;
  float ex = fmaf(sg, nA, muf[0]);
  float ey = fmaf(sg, nB, muf[1]);

  ox = ring ? rx : ex;
  oy = ring ? ry : ey;
  biOut = bi;
}

// ---------------------------------------------------------------------------
// Kernel 2: FOUR adjacent samples per loop iteration (4 independent chains
// for trans-pipe/dep-bubble overlap); 2x float4 xy stores + 1x float4 idx
// store. Math identical to R8 (modulo the guard threshold above).
// ---------------------------------------------------------------------------
__global__ void __launch_bounds__(256)
sample_kernel(const Params* __restrict__ P, float* __restrict__ out, int N) {
#pragma clang fp contract(off)
  float lg[5], cw[5];
  float muf[6], Rsf[3];
  unsigned ky[8];
#pragma unroll
  for (int j = 0; j < 5; ++j) lg[j] = P->logits[j];
#pragma unroll
  for (int j = 0; j < 5; ++j) cw[j] = P->invw[j];
#pragma unroll
  for (int j = 0; j < 6; ++j) muf[j] = (float)P->mu[j];
#pragma unroll
  for (int j = 0; j < 3; ++j) Rsf[j] = (float)P->Rs[j];
#pragma unroll
  for (int j = 0; j < 8; ++j) ky[j] = P->keys[j];

  int tid = blockIdx.x * blockDim.x + threadIdx.x;
  int T = gridDim.x * blockDim.x;
  int QUADS = N >> 2;
  float* idx_out = out + 2 * (size_t)N;

  for (int q = tid; q < QUADS; q += T) {
    float ox0, oy0, ox1, oy1, ox2, oy2, ox3, oy3;
    int b0, b1, b2, b3;
    unsigned s0 = 4u * (unsigned)q;
    do_sample(s0,      lg, cw, muf, Rsf, ky, ox0, oy0, b0);
    do_sample(s0 + 1u, lg, cw, muf, Rsf, ky, ox1, oy1, b1);
    do_sample(s0 + 2u, lg, cw, muf, Rsf, ky, ox2, oy2, b2);
    do_sample(s0 + 3u, lg, cw, muf, Rsf, ky, ox3, oy3, b3);
    reinterpret_cast<float4*>(out)[2 * q + 0] = make_float4(ox0, oy0, ox1, oy1);
    reinterpret_cast<float4*>(out)[2 * q + 1] = make_float4(ox2, oy2, ox3, oy3);
    reinterpret_cast<float4*>(idx_out)[q] =
        make_float4((float)b0, (float)b1, (float)b2, (float)b3);
  }
  // remainder safety (N % 4 != 0 never happens in this harness: N = 2^23)
  int rem_start = QUADS << 2;
  for (int s = rem_start + tid; s < N; s += T) {
    float ox, oy; int bi;
    do_sample((unsigned)s, lg, cw, muf, Rsf, ky, ox, oy, bi);
    reinterpret_cast<float2*>(out)[s] = make_float2(ox, oy);
    idx_out[s] = (float)bi;
  }
}

extern "C" void kernel_launch(void* const* d_in, const int* in_sizes, int n_in,
                              void* d_out, int out_size, void* d_ws, size_t ws_size,
                              hipStream_t stream) {
  const float* c   = (const float*)d_in[0];
  const float* h   = (const float*)d_in[1];
  const float* W1  = (const float*)d_in[2];
  const float* b1  = (const float*)d_in[3];
  const float* W2  = (const float*)d_in[4];
  const float* b2  = (const float*)d_in[5];
  const float* W3  = (const float*)d_in[6];
  const float* b3  = (const float*)d_in[7];
  const float* Wmu = (const float*)d_in[8];
  const float* bmu = (const float*)d_in[9];
  const float* WR  = (const float*)d_in[10];
  const float* bR  = (const float*)d_in[11];
  (void)in_sizes; (void)n_in; (void)ws_size;

  int N = out_size / 3;
  Params* P = (Params*)d_ws;

  hipLaunchKernelGGL(prep_kernel, dim3(1), dim3(256), 0, stream,
                     c, h, W1, b1, W2, b2, W3, b3, Wmu, bmu, WR, bR, P);
  int blocks = 4096;
  hipLaunchKernelGGL(sample_kernel, dim3(blocks), dim3(256), 0, stream,
                     P, (float*)d_out, N);
}

// Round 10
// 164.083 us; speedup vs baseline: 1.0934x; 1.0934x over previous
//
#include <hip/hip_runtime.h>
#include <math.h>

// ---------------------------------------------------------------------------
// Threefry-2x32 (JAX), 20 rounds. Exact integer arithmetic.
// ---------------------------------------------------------------------------
#define TFROT(v, r) __builtin_amdgcn_alignbit((v), (v), 32 - (r))

__device__ __forceinline__ void tf_block(unsigned k0, unsigned k1,
                                         unsigned x0, unsigned x1,
                                         unsigned &o0, unsigned &o1) {
  unsigned ks2 = k0 ^ k1 ^ 0x1BD11BDAu;
  x0 += k0; x1 += k1;
  x0 += x1; x1 = TFROT(x1, 13); x1 ^= x0;
  x0 += x1; x1 = TFROT(x1, 15); x1 ^= x0;
  x0 += x1; x1 = TFROT(x1, 26); x1 ^= x0;
  x0 += x1; x1 = TFROT(x1,  6); x1 ^= x0;
  x0 += k1; x1 += ks2 + 1u;
  x0 += x1; x1 = TFROT(x1, 17); x1 ^= x0;
  x0 += x1; x1 = TFROT(x1, 29); x1 ^= x0;
  x0 += x1; x1 = TFROT(x1, 16); x1 ^= x0;
  x0 += x1; x1 = TFROT(x1, 24); x1 ^= x0;
  x0 += ks2; x1 += k0 + 2u;
  x0 += x1; x1 = TFROT(x1, 13); x1 ^= x0;
  x0 += x1; x1 = TFROT(x1, 15); x1 ^= x0;
  x0 += x1; x1 = TFROT(x1, 26); x1 ^= x0;
  x0 += x1; x1 = TFROT(x1,  6); x1 ^= x0;
  x0 += k0; x1 += k1 + 3u;
  x0 += x1; x1 = TFROT(x1, 17); x1 ^= x0;
  x0 += x1; x1 = TFROT(x1, 29); x1 ^= x0;
  x0 += x1; x1 = TFROT(x1, 16); x1 ^= x0;
  x0 += x1; x1 = TFROT(x1, 24); x1 ^= x0;
  x0 += k1; x1 += ks2 + 4u;
  x0 += x1; x1 = TFROT(x1, 13); x1 ^= x0;
  x0 += x1; x1 = TFROT(x1, 15); x1 ^= x0;
  x0 += x1; x1 = TFROT(x1, 26); x1 ^= x0;
  x0 += x1; x1 = TFROT(x1,  6); x1 ^= x0;
  x0 += ks2; x1 += k0 + 5u;
  o0 = x0; o1 = x1;
}

// partitionable random_bits(32) word for flat index i: out0 ^ out1
__device__ __forceinline__ unsigned tf_bits32(unsigned k0, unsigned k1, unsigned i) {
  unsigned o0, o1;
  tf_block(k0, k1, 0u, i, o0, o1);
  return o0 ^ o1;
}

// ---------------------------------------------------------------------------
// XLA:CPU f32 exp (GenerateVF32Exp — Cephes sequential Horner, UNFUSED).
// ---------------------------------------------------------------------------
__device__ __forceinline__ float xla_exp_f32(float x) {
#pragma clang fp contract(off)
  const float kHi = 88.3762626647950f;
  const float kLo = -88.3762626647949f;
  const float kLog2e = 1.44269504088896341f;
  const float kC1 = 0.693359375f;
  const float kC2 = -2.12194440e-4f;
  const float p0 = 1.9875691500e-4f, p1 = 1.3981999507e-3f,
              p2 = 8.3334519073e-3f, p3 = 4.1665795894e-2f,
              p4 = 1.6666665459e-1f, p5 = 5.0000001201e-1f;
  float xc = fminf(fmaxf(x, kLo), kHi);
  float t = xc * kLog2e;
  t = t + 0.5f;
  float fx = floorf(t);
  float tmp = kC1 * fx;
  float z = kC2 * fx;
  float xr = xc - tmp;
  xr = xr - z;
  z = xr * xr;
  float y = p0 * xr;  y = y + p1;
  y = y * xr;  y = y + p2;
  y = y * xr;  y = y + p3;
  y = y * xr;  y = y + p4;
  y = y * xr;  y = y + p5;
  y = y * z;   y = y + xr;
  y = 1.0f + y;
  int emm0 = (int)fx;
  emm0 = (emm0 + 0x7f) << 23;
  float two_n = __int_as_float(emm0);
  float res = y * two_n;
  return fmaxf(res, x);   // max with ORIGINAL input (XLA)
}

// ---------------------------------------------------------------------------
// XLA:CPU f32 log (GenerateVF32Log — Eigen 3.3 AVX plog port, UNFUSED).
// ---------------------------------------------------------------------------
__device__ __forceinline__ float xla_log_f32(float x) {
#pragma clang fp contract(off)
  const float kSqrtHf = 0.707106781186547524f;
  const float p0 = 7.0376836292e-2f,  p1 = -1.1514610310e-1f,
              p2 = 1.1676998740e-1f,  p3 = -1.2420140846e-1f,
              p4 = 1.4249322787e-1f,  p5 = -1.6668057665e-1f,
              p6 = 2.0000714765e-1f,  p7 = -2.4999993993e-1f,
              p8 = 3.3333331174e-1f;
  const float q1 = -2.12194440e-4f, q2 = 0.693359375f;
  float t0 = fmaxf(x, __uint_as_float(0x00800000u));  // min normal pos
  unsigned ib = __float_as_uint(t0);
  int ei = (int)(ib >> 23) - 0x7f;
  float e = (float)ei;
  e = e + 1.0f;
  t0 = __uint_as_float((ib & 0x807fffffu) | 0x3f000000u);  // mantissa [0.5,1)
  bool m = (t0 < kSqrtHf);
  float tmp1 = m ? t0 : 0.0f;
  t0 = t0 - 1.0f;
  e = e - (m ? 1.0f : 0.0f);
  t0 = t0 + tmp1;
  float x2 = t0 * t0;
  float x3 = x2 * t0;
  float y, y1, y2;
  y  = p0 * t0;  y  = y  + p1;
  y1 = p3 * t0;  y1 = y1 + p4;
  y2 = p6 * t0;  y2 = y2 + p7;
  y  = y  * t0;  y  = y  + p2;
  y1 = y1 * t0;  y1 = y1 + p5;
  y2 = y2 * t0;  y2 = y2 + p8;
  y  = y * x3;   y  = y + y1;
  y  = y * x3;   y  = y + y2;
  y  = y * x3;
  y1 = e * q1;
  float tmp2 = x2 * 0.5f;
  y = y + y1;
  t0 = t0 - tmp2;
  y2 = e * q2;
  t0 = t0 + y;
  t0 = t0 + y2;
  return t0;
}

// uniform [0,1) from 32 random bits, exactly as jax._src.random._uniform
__device__ __forceinline__ float bits_to_f01(unsigned b) {
#pragma clang fp contract(off)
  return __uint_as_float((b >> 9) | 0x3f800000u) - 1.0f;
}

// f32 Giles erfinv — continuous path only (abs slack ~0.1; err ~1e-6)
__device__ __forceinline__ float erfinv_f(float x) {
  float t = fmaf(-x, x, 1.0f);
  float w = -__logf(t);
  float p;
  if (w < 5.0f) {
    float v = w - 2.5f;
    p = 2.81022636e-08f;
    p = fmaf(p, v, 3.43273939e-07f);
    p = fmaf(p, v, -3.5233877e-06f);
    p = fmaf(p, v, -4.39150654e-06f);
    p = fmaf(p, v, 0.00021858087f);
    p = fmaf(p, v, -0.00125372503f);
    p = fmaf(p, v, -0.00417768164f);
    p = fmaf(p, v, 0.246640727f);
    p = fmaf(p, v, 1.50140941f);
  } else {
    float v = __fsqrt_rn(w) - 3.0f;
    p = -0.000200214257f;
    p = fmaf(p, v, 0.000100950558f);
    p = fmaf(p, v, 0.00134934322f);
    p = fmaf(p, v, -0.00367342844f);
    p = fmaf(p, v, 0.00573950773f);
    p = fmaf(p, v, -0.0076224613f);
    p = fmaf(p, v, 0.00943887047f);
    p = fmaf(p, v, 1.00167406f);
    p = fmaf(p, v, 2.83297682f);
  }
  return p * x;
}

struct Params {
  double mu[6];     // mus (3,2) row-major
  double Rs[3];
  float logits[5];  // log(wf) — exact slow-path scores
  float invw[5];    // 1/wf — fast exponential-race coefficients
  unsigned keys[8]; // kcat, kth, kr, keps (2 words each)
};

// ---------------------------------------------------------------------------
// Kernel 1: single-block prep, UNCHANGED bitwise math from passing rounds.
// ---------------------------------------------------------------------------
__global__ void prep_kernel(const float* __restrict__ c, const float* __restrict__ h,
                            const float* __restrict__ W1, const float* __restrict__ b1,
                            const float* __restrict__ W2, const float* __restrict__ b2,
                            const float* __restrict__ W3, const float* __restrict__ b3,
                            const float* __restrict__ Wmu, const float* __restrict__ bmu,
                            const float* __restrict__ WR, const float* __restrict__ bR,
                            Params* __restrict__ P) {
#pragma clang fp contract(off)
  __shared__ float xs[192], z1[128], z2[128], z3[5];
  int t = threadIdx.x;
  if (t < 64) xs[t] = c[t];
  else if (t < 192) xs[t] = h[t - 64];
  __syncthreads();
  if (t < 128) {
    float acc = 0.0f;
    for (int k = 0; k < 192; ++k) { float pr = xs[k] * W1[k * 128 + t]; acc = acc + pr; }
    acc = acc + b1[t];
    float ex = xla_exp_f32(-acc);
    float den = 1.0f + ex;
    float sg = 1.0f / den;
    z1[t] = acc * sg;
  }
  __syncthreads();
  if (t < 128) {
    float acc = 0.0f;
    for (int k = 0; k < 128; ++k) { float pr = z1[k] * W2[k * 128 + t]; acc = acc + pr; }
    acc = acc + b2[t];
    float ex = xla_exp_f32(-acc);
    float den = 1.0f + ex;
    float sg = 1.0f / den;
    z2[t] = acc * sg;
  }
  __syncthreads();
  if (t < 5) {
    float acc = 0.0f;
    for (int k = 0; k < 128; ++k) { float pr = z2[k] * W3[k * 5 + t]; acc = acc + pr; }
    z3[t] = acc + b3[t];
  }
  if (t < 6) {
    double acc = 0.0;
    for (int k = 0; k < 192; ++k) acc += (double)xs[k] * (double)Wmu[k * 6 + t];
    P->mu[t] = acc + (double)bmu[t];
  }
  if (t < 3) {
    double acc = 0.0;
    for (int k = 0; k < 192; ++k) acc += (double)xs[k] * (double)WR[k * 3 + t];
    P->Rs[t] = acc + (double)bR[t];
  }
  __syncthreads();
  if (t == 0) {
    float mx = z3[0];
    for (int j = 1; j < 5; ++j) mx = fmaxf(mx, z3[j]);
    float ev[5];
    float ssum = 0.0f;
    for (int j = 0; j < 5; ++j) {
      float d = z3[j] - mx;
      ev[j] = xla_exp_f32(d);
      ssum = ssum + ev[j];
    }
    float w[5];
    for (int j = 0; j < 5; ++j) w[j] = ev[j] / ssum;
    float wbg = fminf(w[4], 0.15f);
    float rsum = 0.0f;
    for (int j = 0; j < 4; ++j) rsum = rsum + w[j];
    float rs = fmaxf(rsum, 1e-8f);
    float om = 1.0f - wbg;
    float wf[5];
    for (int j = 0; j < 4; ++j) {
      float a = w[j] * om;
      float bq = a / rs;
      wf[j] = bq + 1e-8f;
    }
    wf[4] = wbg + 1e-8f;
    for (int j = 0; j < 5; ++j) {
      P->logits[j] = xla_log_f32(wf[j]);
      P->invw[j] = 1.0f / wf[j];
    }
    unsigned a0, a1;
    tf_block(0u, 42u, 0u, 0u, a0, a1); P->keys[0] = a0; P->keys[1] = a1;  // k_cat
    tf_block(0u, 42u, 0u, 1u, a0, a1); P->keys[2] = a0; P->keys[3] = a1;  // k_th
    tf_block(0u, 42u, 0u, 2u, a0, a1); P->keys[4] = a0; P->keys[5] = a1;  // k_r
    tf_block(0u, 42u, 0u, 3u, a0, a1); P->keys[6] = a0; P->keys[7] = a1;  // k_eps
  }
}

// ---------------------------------------------------------------------------
// One sample: exponential-race categorical (guarded exact recompute) +
// branch-free ring/eps tail. Arithmetic byte-identical to the passing R8;
// guard rel-margin 1e-4 (validated in R9: absmax unchanged, only shifts
// lanes between fast/exact paths, never the chosen index).
// ---------------------------------------------------------------------------
__device__ __forceinline__ void do_sample(unsigned sU,
                                          const float* lg, const float* cw,
                                          const float* muf, const float* Rsf,
                                          const unsigned* ky,
                                          float& ox, float& oy, int& biOut) {
#pragma clang fp contract(off)
  const float TINYF = __uint_as_float(0x00800000u);   // f32 tiny (min normal)
  const float LOF   = __uint_as_float(0xBF7FFFFFu);   // nextafter(-1,0)
  const float SQRT2F = 1.4142135623730951f;

  unsigned base = 5u * sU;
  unsigned bb[5];
  int bi = 0;
  float m1 = __builtin_inff();
  float m2 = __builtin_inff();
#pragma unroll
  for (int j = 0; j < 5; ++j) {
    unsigned b = tf_bits32(ky[0], ky[1], base + (unsigned)j);
    bb[j] = b;
    float u0 = bits_to_f01(b);
    float e2 = -__log2f(u0);           // +inf when u0 == 0 (never argmin)
    float m = e2 * cw[j];
    bool lt = m < m1;
    float old1 = m1;
    m1 = lt ? m : m1;
    m2 = lt ? old1 : fminf(m2, m);
    bi = lt ? j : bi;
  }
  // guard: relative margin, tiny-m floor (hw-log error regime), inf runner-up
  bool slow = (m2 - m1 < 1e-4f * m2) || (m1 < 1e-4f) || (m2 > 1e37f);
  if (slow) {
    // exact recompute: bitwise-XLA chain, first-max-wins
    int best = 0;
    float bestv = -__builtin_inff();
#pragma unroll
    for (int j = 0; j < 5; ++j) {
      float u0 = bits_to_f01(bb[j]);
      float u = u0 + TINYF;
      u = fmaxf(TINYF, u);
      float l1 = xla_log_f32(u);
      float nl1 = -l1;
      float l2 = xla_log_f32(nl1);
      float g = -l2;
      float sc = g + lg[j];
      if (sc > bestv) { bestv = sc; best = j; }
    }
    bi = best;
  }

  // branch-free tail: 2 shared threefry blocks, both results, select
  bool ring = bi < 3;
  unsigned cA = ring ? sU : 2u * sU;
  unsigned cB = ring ? sU : 2u * sU + 1u;
  unsigned kA0 = ring ? ky[2] : ky[6];
  unsigned kA1 = ring ? ky[3] : ky[7];
  unsigned kB0 = ring ? ky[4] : ky[6];
  unsigned kB1 = ring ? ky[5] : ky[7];
  unsigned bA = tf_bits32(kA0, kA1, cA);
  unsigned bB = tf_bits32(kB0, kB1, cB);

  float a01 = bits_to_f01(bA);         // ring: theta in revolutions; eps: uA
  float b01 = bits_to_f01(bB);
  float uB = fmaxf(LOF, fmaf(b01, 2.0f, LOF));
  float nB = SQRT2F * erfinv_f(uB);    // ring: r-noise; eps: y-normal

  // ring result (hw sin/cos take revolutions: sin(2*pi*a01))
  float Rb  = (bi == 0) ? Rsf[0] : ((bi == 1) ? Rsf[1] : Rsf[2]);
  float mxr = (bi == 0) ? muf[0] : ((bi == 1) ? muf[2] : muf[4]);
  float myr = (bi == 0) ? muf[1] : ((bi == 1) ? muf[3] : muf[5]);
  float r = fmaf(0.02f, nB, Rb);
  float rx = fmaf(r, __builtin_amdgcn_cosf(a01), mxr);
  float ry = fmaf(r, __builtin_amdgcn_sinf(a01), myr);

  // eps result
  float uA = fmaxf(LOF, fmaf(a01, 2.0f, LOF));
  float nA = SQRT2F * erfinv_f(uA);
  float sg = (bi == 3) ? 0.01f : 0.94f;
  float ex = fmaf(sg, nA, muf[0]);
  float ey = fmaf(sg, nB, muf[1]);

  ox = ring ? rx : ex;
  oy = ring ? ry : ey;
  biOut = bi;
}

// ---------------------------------------------------------------------------
// Kernel 2: two adjacent samples per loop iteration (R8 structure — proven
// best; 4-way trips AMDGPUPromoteAlloca into LDS-backed spills, R9's 1.9M
// bank conflicts). float4 xy store + float2 idx store.
// ---------------------------------------------------------------------------
__global__ void __launch_bounds__(256)
sample_kernel(const Params* __restrict__ P, float* __restrict__ out, int N) {
#pragma clang fp contract(off)
  float lg[5], cw[5];
  float muf[6], Rsf[3];
  unsigned ky[8];
#pragma unroll
  for (int j = 0; j < 5; ++j) lg[j] = P->logits[j];
#pragma unroll
  for (int j = 0; j < 5; ++j) cw[j] = P->invw[j];
#pragma unroll
  for (int j = 0; j < 6; ++j) muf[j] = (float)P->mu[j];
#pragma unroll
  for (int j = 0; j < 3; ++j) Rsf[j] = (float)P->Rs[j];
#pragma unroll
  for (int j = 0; j < 8; ++j) ky[j] = P->keys[j];

  int tid = blockIdx.x * blockDim.x + threadIdx.x;
  int T = gridDim.x * blockDim.x;
  int PAIRS = N >> 1;
  float* idx_out = out + 2 * (size_t)N;

  for (int p = tid; p < PAIRS; p += T) {
    float oxA, oyA, oxB, oyB;
    int biA, biB;
    unsigned sA = 2u * (unsigned)p;
    do_sample(sA,      lg, cw, muf, Rsf, ky, oxA, oyA, biA);
    do_sample(sA + 1u, lg, cw, muf, Rsf, ky, oxB, oyB, biB);
    reinterpret_cast<float4*>(out)[p] = make_float4(oxA, oyA, oxB, oyB);
    reinterpret_cast<float2*>(idx_out)[p] = make_float2((float)biA, (float)biB);
  }
  // odd-N safety (N is even in this harness; branch never taken)
  if ((N & 1) && tid == 0) {
    float ox, oy; int bi;
    do_sample((unsigned)(N - 1), lg, cw, muf, Rsf, ky, ox, oy, bi);
    reinterpret_cast<float2*>(out)[N - 1] = make_float2(ox, oy);
    idx_out[N - 1] = (float)bi;
  }
}

extern "C" void kernel_launch(void* const* d_in, const int* in_sizes, int n_in,
                              void* d_out, int out_size, void* d_ws, size_t ws_size,
                              hipStream_t stream) {
  const float* c   = (const float*)d_in[0];
  const float* h   = (const float*)d_in[1];
  const float* W1  = (const float*)d_in[2];
  const float* b1  = (const float*)d_in[3];
  const float* W2  = (const float*)d_in[4];
  const float* b2  = (const float*)d_in[5];
  const float* W3  = (const float*)d_in[6];
  const float* b3  = (const float*)d_in[7];
  const float* Wmu = (const float*)d_in[8];
  const float* bmu = (const float*)d_in[9];
  const float* WR  = (const float*)d_in[10];
  const float* bR  = (const float*)d_in[11];
  (void)in_sizes; (void)n_in; (void)ws_size;

  int N = out_size / 3;
  Params* P = (Params*)d_ws;

  hipLaunchKernelGGL(prep_kernel, dim3(1), dim3(256), 0, stream,
                     c, h, W1, b1, W2, b2, W3, b3, Wmu, bmu, WR, bR, P);
  int blocks = 4096;
  hipLaunchKernelGGL(sample_kernel, dim3(blocks), dim3(256), 0, stream,
                     P, (float*)d_out, N);
}